// Round 5
// baseline (3961.436 us; speedup 1.0000x reference)
//
#include <hip/hip_runtime.h>
#include <math.h>

#define NFFT   1024
#define NHALF  512
#define HOPSZ  256
#define NMELS  80
#define NFREQ  513
#define BATCH  8
#define TFRAMES 1024
#define PADW   512
#define LPAD   (NFFT + (TFRAMES - 1) * HOPSZ)   // 262912
#define LOUT   (LPAD - 2 * PADW)                // 261888
#define NITER  60
#define PI_D   3.14159265358979323846

// LDS anti-bank-conflict padding: +1 word every 32
#define PAD(p) ((p) + ((p) >> 5))
#define NPAD   (NHALF + (NHALF >> 5))           // 528

// ---------------------------------------------------------------- init tables
// tw1024[j] = e^{-2pi i j/1024} (j<512) ; t5[j] = e^{-2pi i j/512} (j<128, radix-4 twiddles)
__global__ void k_init_tables(float* __restrict__ twr, float* __restrict__ twi,
                              float* __restrict__ t5r, float* __restrict__ t5i,
                              float* __restrict__ win) {
    int j = blockIdx.x * 256 + threadIdx.x;
    if (j < NHALF) {
        double th = -2.0 * PI_D * (double)j / (double)NFFT;
        twr[j] = (float)cos(th);
        twi[j] = (float)sin(th);
    }
    if (j < 128) {
        double th = -2.0 * PI_D * (double)j / 512.0;
        t5r[j] = (float)cos(th);
        t5i[j] = (float)sin(th);
    }
    if (j < NFFT) {
        win[j] = (float)(0.5 - 0.5 * cos(2.0 * PI_D * (double)j / (double)NFFT));
    }
}

__global__ void k_env(const float* __restrict__ win, float* __restrict__ envinv) {
    int i = blockIdx.x * 256 + threadIdx.x;
    if (i >= LPAD) return;
    int thi = i / HOPSZ; if (thi > TFRAMES - 1) thi = TFRAMES - 1;
    int d = i - (NFFT - 1);
    int tlo = (d > 0) ? (d + HOPSZ - 1) / HOPSZ : 0;
    float e = 0.f;
    for (int t = tlo; t <= thi; ++t) { float w = win[i - t * HOPSZ]; e += w * w; }
    envinv[i] = (e > 1e-11f) ? (1.0f / e) : 1.0f;
}

// fbT[m*513+k] = fb[k*80+m]
__global__ void k_fbt(const float* __restrict__ fb, float* __restrict__ fbT) {
    int i = blockIdx.x * 256 + threadIdx.x;
    if (i < NFREQ * NMELS) {
        int k = i / NMELS, m = i - k * NMELS;
        fbT[m * NFREQ + k] = fb[i];
    }
}

// mag[(b*1024+t)*513+k], tiled 16 t per block; expf folded into tile load
__global__ __launch_bounds__(256) void k_mag(const float* __restrict__ mel,
                                             const float* __restrict__ fbT,
                                             float* __restrict__ mag) {
    __shared__ float sm[NMELS * 16];               // [m][tt]
    int b = blockIdx.y, t0 = blockIdx.x * 16, tid = threadIdx.x;
    for (int idx = tid; idx < NMELS * 16; idx += 256) {
        int m = idx >> 4, tt = idx & 15;
        sm[idx] = expf(mel[(size_t)(b * NMELS + m) * TFRAMES + (t0 + tt)]);
    }
    __syncthreads();
    for (int k = tid; k < NFREQ; k += 256) {
        float acc[16];
        #pragma unroll
        for (int tt = 0; tt < 16; ++tt) acc[tt] = 0.f;
        for (int m = 0; m < NMELS; ++m) {
            float w = fbT[m * NFREQ + k];
            #pragma unroll
            for (int tt = 0; tt < 16; ++tt) acc[tt] += w * sm[m * 16 + tt];
        }
        #pragma unroll
        for (int tt = 0; tt < 16; ++tt)
            mag[(size_t)((b << 10) + t0 + tt) * NFREQ + k] = fmaxf(acc[tt], 0.f);
    }
}

// ------------------------------------------------- Stockham radix-2, 512 pts
// (unpadded, 256 threads — used only by k_init_frames; verified in round 4)
__device__ __forceinline__ void fft512_r2(float* xr, float* xi, float* yr, float* yi,
                                          const float* t5r, const float* t5i,
                                          int tid, float sgn) {
    float *ar = xr, *ai = xi, *br = yr, *bi = yi;
    #pragma unroll
    for (int stage = 0; stage < 9; ++stage) {
        int s = 1 << stage;
        __syncthreads();
        int bb = tid;
        int hi = bb & ~(s - 1);
        int o1 = bb + hi;
        float x0r = ar[bb],       x0i = ai[bb];
        float x1r = ar[bb + 256], x1i = ai[bb + 256];
        float wr = t5r[hi], wi = sgn * t5i[hi];
        float sr = x0r - x1r, si = x0i - x1i;
        br[o1]     = x0r + x1r;
        bi[o1]     = x0i + x1i;
        br[o1 + s] = sr * wr - si * wi;
        bi[o1 + s] = sr * wi + si * wr;
        float* t0 = ar; ar = br; br = t0;
        float* t1 = ai; ai = bi; bi = t1;
    }
}

// --------------------------- Stockham DIF mixed radix [4,4,4,4,2], 512 pts
// 128 threads, PADded LDS. Table t5 = W_512 (128 entries, hi<=127).
// sgn=+1 FORWARD, sgn=-1 INVERSE (unscaled). Input in (xr,xi), output in (yr,yi).
// DIF stage (R,s): read stride 512/R, DFT_R, twiddle W_512^{k*hi} after,
// write o1 + k*s with o1 = j + (R-1)*hi, hi = (j/s)*s.  Last stage twiddle-free.
__device__ __forceinline__ void fft512_m(float* xr, float* xi, float* yr, float* yi,
                                         const float* t5r, const float* t5i,
                                         int tid, float sgn) {
    float *ar = xr, *ai = xi, *br = yr, *bi = yi;
    #pragma unroll
    for (int st = 0; st < 4; ++st) {
        int s = 1 << (2 * st);                 // 1,4,16,64
        __syncthreads();
        int j = tid;                           // [0,128)
        int hi = j & ~(s - 1);
        int o1 = j + 3 * hi;
        float v0r = ar[PAD(j)],       v0i = ai[PAD(j)];
        float v1r = ar[PAD(j + 128)], v1i = ai[PAD(j + 128)];
        float v2r = ar[PAD(j + 256)], v2i = ai[PAD(j + 256)];
        float v3r = ar[PAD(j + 384)], v3i = ai[PAD(j + 384)];
        float a_r = v0r + v2r, a_i = v0i + v2i;
        float b_r = v0r - v2r, b_i = v0i - v2i;
        float c_r = v1r + v3r, c_i = v1i + v3i;
        float d_r = v1r - v3r, d_i = v1i - v3i;
        float X0r = a_r + c_r, X0i = a_i + c_i;
        float X2r = a_r - c_r, X2i = a_i - c_i;
        float X1r = b_r + sgn * d_i, X1i = b_i - sgn * d_r;   // b - i*d (fwd)
        float X3r = b_r - sgn * d_i, X3i = b_i + sgn * d_r;   // b + i*d (fwd)
        float w1r = t5r[hi], w1i = sgn * t5i[hi];
        float w2r = w1r * w1r - w1i * w1i, w2i = 2.f * w1r * w1i;
        float w3r = w2r * w1r - w2i * w1i, w3i = w2r * w1i + w2i * w1r;
        br[PAD(o1)]         = X0r;
        bi[PAD(o1)]         = X0i;
        br[PAD(o1 + s)]     = X1r * w1r - X1i * w1i;
        bi[PAD(o1 + s)]     = X1r * w1i + X1i * w1r;
        br[PAD(o1 + 2*s)]   = X2r * w2r - X2i * w2i;
        bi[PAD(o1 + 2*s)]   = X2r * w2i + X2i * w2r;
        br[PAD(o1 + 3*s)]   = X3r * w3r - X3i * w3i;
        bi[PAD(o1 + 3*s)]   = X3r * w3i + X3i * w3r;
        float* t0 = ar; ar = br; br = t0;
        float* t1 = ai; ai = bi; bi = t1;
    }
    // final radix-2 stage, s=256: twiddle-free (hi=0 for all j<256)
    __syncthreads();
    #pragma unroll
    for (int r = 0; r < 2; ++r) {
        int j = tid + r * 128;                 // [0,256)
        float x0r = ar[PAD(j)],       x0i = ai[PAD(j)];
        float x1r = ar[PAD(j + 256)], x1i = ai[PAD(j + 256)];
        br[PAD(j)]       = x0r + x1r;
        bi[PAD(j)]       = x0i + x1i;
        br[PAD(j + 256)] = x0r - x1r;
        bi[PAD(j + 256)] = x0i - x1i;
    }
    // 4 swaps + final write: result ends in (yr,yi)
}

// ------------------------------- initial frames: irfft(mag * e^{i2pi ang}) * win
__global__ __launch_bounds__(256) void k_init_frames(
        const float* __restrict__ mag, const float* __restrict__ ang,
        const float* __restrict__ gtwr, const float* __restrict__ gtwi,
        const float* __restrict__ win, float* __restrict__ frames) {
    __shared__ float Xr[NHALF], Xi[NHALF], Yr[NHALF], Yi[NHALF];
    __shared__ float t5r[256], t5i[256];
    int f = blockIdx.x; int b = f >> 10; int t = f & 1023;
    int tid = threadIdx.x;
    // build W_512 table (256 entries) from W_1024 table: W_512^j = W_1024^{2j}
    t5r[tid] = gtwr[2 * tid >= 512 ? 2 * tid - 512 : 2 * tid] * (2 * tid >= 512 ? -1.f : 1.f);
    t5i[tid] = gtwi[2 * tid >= 512 ? 2 * tid - 512 : 2 * tid] * (2 * tid >= 512 ? -1.f : 1.f);
    const float* mrow = mag + (size_t)f * NFREQ;
    const float TWO_PI = 6.283185307179586477f;
    if (tid == 0) {
        float a0, s0, c0;
        a0 = ang[((size_t)(b * NFREQ + 0)) * TFRAMES + t] * TWO_PI;
        sincosf(a0, &s0, &c0);
        float p0 = mrow[0] * c0;
        a0 = ang[((size_t)(b * NFREQ + 512)) * TFRAMES + t] * TWO_PI;
        sincosf(a0, &s0, &c0);
        float p512 = mrow[512] * c0;
        Xr[0] = 0.5f * (p0 + p512);
        Xi[0] = 0.5f * (p0 - p512);
        a0 = ang[((size_t)(b * NFREQ + 256)) * TFRAMES + t] * TWO_PI;
        sincosf(a0, &s0, &c0);
        Xr[256] = mrow[256] * c0;
        Xi[256] = -(mrow[256] * s0);
    } else {
        int k = tid, j = 512 - k;
        float ak = ang[((size_t)(b * NFREQ + k)) * TFRAMES + t] * TWO_PI;
        float aj = ang[((size_t)(b * NFREQ + j)) * TFRAMES + t] * TWO_PI;
        float sk, ck, sj, cj;
        sincosf(ak, &sk, &ck); sincosf(aj, &sj, &cj);
        float pkr = mrow[k] * ck, pki = mrow[k] * sk;
        float pjr = mrow[j] * cj, pji = mrow[j] * sj;
        float Wr = gtwr[k], Wi = gtwi[k];
        float Cr = 0.5f * (pkr + pjr), Ci = 0.5f * (pki - pji);
        float Dr = 0.5f * (pkr - pjr), Di = 0.5f * (pki + pji);
        float U = Wr * Di - Wi * Dr, V = Wr * Dr + Wi * Di;
        Xr[k] = Cr - U;  Xi[k] = Ci + V;
        Xr[j] = Cr + U;  Xi[j] = -Ci + V;
    }
    fft512_r2(Xr, Xi, Yr, Yi, t5r, t5i, tid, -1.f);   // inverse; result in Y
    __syncthreads();
    float2* fr2 = (float2*)(frames + (size_t)f * NFFT);
    const float2* w2p = (const float2*)win;
    const float SC = 1.0f / 512.0f;
    #pragma unroll
    for (int r = 0; r < 2; ++r) {
        int m = tid + r * 256;
        float2 w2 = w2p[m];
        fr2[m] = make_float2(Yr[m] * w2.x * SC, Yi[m] * w2.y * SC);
    }
}

// ------------------- overlap-add: frames -> signal (final output only)
__global__ void k_ola(const float* __restrict__ frames, const float* __restrict__ envinv,
                      float* __restrict__ out) {
    int i = blockIdx.x * 256 + threadIdx.x;
    int b = blockIdx.y;
    if (i >= LOUT) return;
    int ii = i + PADW;
    int thi = ii >> 8; if (thi > TFRAMES - 1) thi = TFRAMES - 1;
    int d = ii - (NFFT - 1);
    int tlo = (d > 0) ? ((d + 255) >> 8) : 0;
    float acc = 0.f;
    const float* fb_ = frames + (size_t)b * TFRAMES * NFFT;
    for (int t = tlo; t <= thi; ++t) acc += fb_[t * NFFT + (ii - t * HOPSZ)];
    out[(size_t)b * LOUT + i] = acc * envinv[ii];
}

// ---- fused GL step: OLA(frames_in)->window gather -> rfft -> project -> irfft -> frames_out
// 128 threads/block, one frame per block. frames ping-pong (in != out).
__global__ __launch_bounds__(128) void k_gl(
        const float* __restrict__ fin, const float* __restrict__ mag,
        const float* __restrict__ envinv,
        const float* __restrict__ gtwr, const float* __restrict__ gtwi,
        const float* __restrict__ gt5r, const float* __restrict__ gt5i,
        const float* __restrict__ win, float* __restrict__ fout) {
    __shared__ float Xr[NPAD], Xi[NPAD], Yr[NPAD], Yi[NPAD];
    __shared__ float t5r[128], t5i[128];
    int f = blockIdx.x; int b = f >> 10; int t = f & 1023;
    int tid = threadIdx.x;
    t5r[tid] = gt5r[tid]; t5i[tid] = gt5i[tid];
    const float* fb_ = fin + (size_t)b * TFRAMES * NFFT;
    const float2* w2p = (const float2*)win;
    int base = t * HOPSZ - PADW;               // window start, unpadded coords
    // gather + OLA + window, packed: z[m] = s[2m]w[2m] + i s[2m+1]w[2m+1]
    #pragma unroll
    for (int r = 0; r < 4; ++r) {
        int m = tid + r * 128;                 // [0,512)
        float2 w2 = w2p[m];
        float vals[2];
        #pragma unroll
        for (int h = 0; h < 2; ++h) {
            int u = base + 2 * m + h;
            if (u < 0) u = -u;
            else if (u >= LOUT) u = 2 * LOUT - 2 - u;
            int ii = u + PADW;
            int thi = ii >> 8; if (thi > TFRAMES - 1) thi = TFRAMES - 1;
            int d = ii - (NFFT - 1);
            int tlo = (d > 0) ? ((d + 255) >> 8) : 0;
            // frame tt contributes fb_[tt*1024 + ii - 256*tt] = fb_[ii + 768*tt]
            float acc = 0.f;
            #pragma unroll
            for (int c = 0; c < 4; ++c) {
                int tt = tlo + c;
                if (tt <= thi) acc += fb_[ii + 768 * tt];
            }
            vals[h] = acc * envinv[ii];
        }
        Xr[PAD(m)] = vals[0] * w2.x;
        Xi[PAD(m)] = vals[1] * w2.y;
    }
    fft512_m(Xr, Xi, Yr, Yi, t5r, t5i, tid, +1.f);   // forward; Z in Y
    __syncthreads();
    // unpack rfft bins, project to mag, repack inverse input into X
    // (no barriers in here: reads Y / writes X at disjoint indices; fft's
    //  stage-0 barrier provides ordering — round-3 lesson)
    const float* mrow = mag + (size_t)f * NFREQ;
    if (tid == 0) {
        float Z0r = Yr[PAD(0)], Z0i = Yi[PAD(0)];
        float X0 = Z0r + Z0i, X512 = Z0r - Z0i;
        float p0   = mrow[0]   * X0   / (fabsf(X0)   + 1e-8f);
        float p512 = mrow[512] * X512 / (fabsf(X512) + 1e-8f);
        float Zcr = Yr[PAD(256)], Zci = Yi[PAD(256)];
        float X256r = Zcr, X256i = -Zci;
        float sc = mrow[256] / (sqrtf(X256r * X256r + X256i * X256i) + 1e-8f);
        Xr[PAD(0)] = 0.5f * (p0 + p512);
        Xi[PAD(0)] = 0.5f * (p0 - p512);
        Xr[PAD(256)] = X256r * sc;
        Xi[PAD(256)] = -(X256i * sc);
    }
    #pragma unroll
    for (int q = 0; q < 2; ++q) {
        int k = tid + q * 128;                 // covers [0,256); k=0 skipped
        if (k == 0) continue;
        int j = 512 - k;
        float Zar = Yr[PAD(k)], Zai = Yi[PAD(k)];
        float Zbr = Yr[PAD(j)], Zbi = Yi[PAD(j)];
        float Ar = 0.5f * (Zar + Zbr), Ai = 0.5f * (Zai - Zbi);
        float Br = 0.5f * (Zar - Zbr), Bi = 0.5f * (Zai + Zbi);
        float Wr = gtwr[k], Wi = gtwi[k];
        float P = Wr * Bi + Wi * Br, Q = Wr * Br - Wi * Bi;
        float Xkr = Ar + P, Xki = Ai - Q;
        float Xjr = Ar - P, Xji = -Ai - Q;
        float sck = mrow[k] / (sqrtf(Xkr * Xkr + Xki * Xki) + 1e-8f);
        float scj = mrow[j] / (sqrtf(Xjr * Xjr + Xji * Xji) + 1e-8f);
        float pkr = Xkr * sck, pki = Xki * sck;
        float pjr = Xjr * scj, pji = Xji * scj;
        float Cr = 0.5f * (pkr + pjr), Ci = 0.5f * (pki - pji);
        float Dr = 0.5f * (pkr - pjr), Di = 0.5f * (pki + pji);
        float U = Wr * Di - Wi * Dr, V = Wr * Dr + Wi * Di;
        Xr[PAD(k)] = Cr - U;  Xi[PAD(k)] = Ci + V;
        Xr[PAD(j)] = Cr + U;  Xi[PAD(j)] = -Ci + V;
    }
    fft512_m(Xr, Xi, Yr, Yi, t5r, t5i, tid, -1.f);   // inverse; z in Y
    __syncthreads();
    float2* fr2 = (float2*)(fout + (size_t)f * NFFT);
    const float SC = 1.0f / 512.0f;
    #pragma unroll
    for (int r = 0; r < 4; ++r) {
        int m = tid + r * 128;
        float2 w2 = w2p[m];
        fr2[m] = make_float2(Yr[PAD(m)] * w2.x * SC, Yi[PAD(m)] * w2.y * SC);
    }
}

// ---------------------------------------------------------------------- host
extern "C" void kernel_launch(void* const* d_in, const int* in_sizes, int n_in,
                              void* d_out, int out_size, void* d_ws, size_t ws_size,
                              hipStream_t stream) {
    const float* mel = (const float*)d_in[0];   // (8, 80, 1024)
    const float* ang = (const float*)d_in[1];   // (8, 513, 1024)
    const float* fb  = (const float*)d_in[2];   // (513, 80)
    float* ws = (float*)d_ws;

    float* twr    = ws;                                   // 512   (W_1024)
    float* twi    = twr + NHALF;                          // 512
    float* t5r    = twi + NHALF;                          // 128   (W_512, radix-4)
    float* t5i    = t5r + 128;                            // 128
    float* win    = t5i + 128;                            // 1024
    float* fbT    = win + NFFT;                           // 80*513
    float* envinv = fbT + NMELS * NFREQ;                  // LPAD
    float* mag    = envinv + LPAD;                        // 8*1024*513
    float* framesA = mag + (size_t)BATCH * TFRAMES * NFREQ;   // 8*1024*1024
    float* framesB = framesA + (size_t)BATCH * TFRAMES * NFFT;// 8*1024*1024
    float* out    = (float*)d_out;

    k_init_tables<<<4, 256, 0, stream>>>(twr, twi, t5r, t5i, win);
    k_env<<<(LPAD + 255) / 256, 256, 0, stream>>>(win, envinv);
    k_fbt<<<(NFREQ * NMELS + 255) / 256, 256, 0, stream>>>(fb, fbT);
    {
        dim3 g(TFRAMES / 16, BATCH);
        k_mag<<<g, 256, 0, stream>>>(mel, fbT, mag);
    }
    k_init_frames<<<BATCH * TFRAMES, 256, 0, stream>>>(mag, ang, twr, twi, win, framesA);

    float* fin = framesA;
    float* fout = framesB;
    for (int it = 0; it < NITER; ++it) {
        k_gl<<<BATCH * TFRAMES, 128, 0, stream>>>(fin, mag, envinv, twr, twi,
                                                  t5r, t5i, win, fout);
        float* tmp = fin; fin = fout; fout = tmp;
    }
    // NITER even -> final frames in framesA (== fin after last swap)
    dim3 olag((LOUT + 255) / 256, BATCH);
    k_ola<<<olag, 256, 0, stream>>>(fin, envinv, out);
}

// Round 6
// 2626.930 us; speedup vs baseline: 1.5080x; 1.5080x over previous
//
#include <hip/hip_runtime.h>
#include <math.h>

#define NFFT   1024
#define NHALF  512
#define HOPSZ  256
#define NMELS  80
#define NFREQ  513
#define BATCH  8
#define TFRAMES 1024
#define PADW   512
#define LPAD   (NFFT + (TFRAMES - 1) * HOPSZ)   // 262912
#define LOUT   (LPAD - 2 * PADW)                // 261888
#define NITER  60
#define PI_D   3.14159265358979323846

#define CHUNKF 4                                // frames per chunk
#define CSPAN  1792                             // 1024 + 3*256
#define NCHUNK (TFRAMES / CHUNKF)               // 256

// LDS anti-bank-conflict padding: +1 word every 32
#define PAD(p) ((p) + ((p) >> 5))
#define NPAD   (NHALF + (NHALF >> 5))           // 528

// ---------------------------------------------------------------- init tables
// tw1024[j] = e^{-2pi i j/1024} (j<512) ; t5[j] = e^{-2pi i j/512} (j<128)
__global__ void k_init_tables(float* __restrict__ twr, float* __restrict__ twi,
                              float* __restrict__ t5r, float* __restrict__ t5i,
                              float* __restrict__ win) {
    int j = blockIdx.x * 256 + threadIdx.x;
    if (j < NHALF) {
        double th = -2.0 * PI_D * (double)j / (double)NFFT;
        twr[j] = (float)cos(th);
        twi[j] = (float)sin(th);
    }
    if (j < 128) {
        double th = -2.0 * PI_D * (double)j / 512.0;
        t5r[j] = (float)cos(th);
        t5i[j] = (float)sin(th);
    }
    if (j < NFFT) {
        win[j] = (float)(0.5 - 0.5 * cos(2.0 * PI_D * (double)j / (double)NFFT));
    }
}

__global__ void k_env(const float* __restrict__ win, float* __restrict__ envinv) {
    int i = blockIdx.x * 256 + threadIdx.x;
    if (i >= LPAD) return;
    int thi = i / HOPSZ; if (thi > TFRAMES - 1) thi = TFRAMES - 1;
    int d = i - (NFFT - 1);
    int tlo = (d > 0) ? (d + HOPSZ - 1) / HOPSZ : 0;
    float e = 0.f;
    for (int t = tlo; t <= thi; ++t) { float w = win[i - t * HOPSZ]; e += w * w; }
    envinv[i] = (e > 1e-11f) ? (1.0f / e) : 1.0f;
}

// fbT[m*513+k] = fb[k*80+m]
__global__ void k_fbt(const float* __restrict__ fb, float* __restrict__ fbT) {
    int i = blockIdx.x * 256 + threadIdx.x;
    if (i < NFREQ * NMELS) {
        int k = i / NMELS, m = i - k * NMELS;
        fbT[m * NFREQ + k] = fb[i];
    }
}

// mag[(b*1024+t)*513+k], tiled 16 t per block; expf folded into tile load
__global__ __launch_bounds__(256) void k_mag(const float* __restrict__ mel,
                                             const float* __restrict__ fbT,
                                             float* __restrict__ mag) {
    __shared__ float sm[NMELS * 16];               // [m][tt]
    int b = blockIdx.y, t0 = blockIdx.x * 16, tid = threadIdx.x;
    for (int idx = tid; idx < NMELS * 16; idx += 256) {
        int m = idx >> 4, tt = idx & 15;
        sm[idx] = expf(mel[(size_t)(b * NMELS + m) * TFRAMES + (t0 + tt)]);
    }
    __syncthreads();
    for (int k = tid; k < NFREQ; k += 256) {
        float acc[16];
        #pragma unroll
        for (int tt = 0; tt < 16; ++tt) acc[tt] = 0.f;
        for (int m = 0; m < NMELS; ++m) {
            float w = fbT[m * NFREQ + k];
            #pragma unroll
            for (int tt = 0; tt < 16; ++tt) acc[tt] += w * sm[m * 16 + tt];
        }
        #pragma unroll
        for (int tt = 0; tt < 16; ++tt)
            mag[(size_t)((b << 10) + t0 + tt) * NFREQ + k] = fmaxf(acc[tt], 0.f);
    }
}

// --------------------------- Stockham DIF mixed radix [4,4,4,4,2], 512 pts
// 128 threads (group-local l), PADded LDS. t5 = W_512 (128 entries).
// sgn=+1 FORWARD, sgn=-1 INVERSE (unscaled). Input (xr,xi) -> output (yr,yi).
// Correctness verified end-to-end in round 5. Barriers are block-wide; all
// groups execute identical stage sequences in lockstep.
__device__ __forceinline__ void fft512_m(float* xr, float* xi, float* yr, float* yi,
                                         const float* t5r, const float* t5i,
                                         int l, float sgn) {
    float *ar = xr, *ai = xi, *br = yr, *bi = yi;
    #pragma unroll
    for (int st = 0; st < 4; ++st) {
        int s = 1 << (2 * st);                 // 1,4,16,64
        __syncthreads();
        int j = l;                             // [0,128)
        int hi = j & ~(s - 1);
        int o1 = j + 3 * hi;
        float v0r = ar[PAD(j)],       v0i = ai[PAD(j)];
        float v1r = ar[PAD(j + 128)], v1i = ai[PAD(j + 128)];
        float v2r = ar[PAD(j + 256)], v2i = ai[PAD(j + 256)];
        float v3r = ar[PAD(j + 384)], v3i = ai[PAD(j + 384)];
        float a_r = v0r + v2r, a_i = v0i + v2i;
        float b_r = v0r - v2r, b_i = v0i - v2i;
        float c_r = v1r + v3r, c_i = v1i + v3i;
        float d_r = v1r - v3r, d_i = v1i - v3i;
        float X0r = a_r + c_r, X0i = a_i + c_i;
        float X2r = a_r - c_r, X2i = a_i - c_i;
        float X1r = b_r + sgn * d_i, X1i = b_i - sgn * d_r;
        float X3r = b_r - sgn * d_i, X3i = b_i + sgn * d_r;
        float w1r = t5r[hi], w1i = sgn * t5i[hi];
        float w2r = w1r * w1r - w1i * w1i, w2i = 2.f * w1r * w1i;
        float w3r = w2r * w1r - w2i * w1i, w3i = w2r * w1i + w2i * w1r;
        br[PAD(o1)]         = X0r;
        bi[PAD(o1)]         = X0i;
        br[PAD(o1 + s)]     = X1r * w1r - X1i * w1i;
        bi[PAD(o1 + s)]     = X1r * w1i + X1i * w1r;
        br[PAD(o1 + 2*s)]   = X2r * w2r - X2i * w2i;
        bi[PAD(o1 + 2*s)]   = X2r * w2i + X2i * w2r;
        br[PAD(o1 + 3*s)]   = X3r * w3r - X3i * w3i;
        bi[PAD(o1 + 3*s)]   = X3r * w3i + X3i * w3r;
        float* t0 = ar; ar = br; br = t0;
        float* t1 = ai; ai = bi; bi = t1;
    }
    __syncthreads();
    #pragma unroll
    for (int r = 0; r < 2; ++r) {              // final radix-2, twiddle-free
        int j = l + r * 128;
        float x0r = ar[PAD(j)],       x0i = ai[PAD(j)];
        float x1r = ar[PAD(j + 256)], x1i = ai[PAD(j + 256)];
        br[PAD(j)]       = x0r + x1r;
        bi[PAD(j)]       = x0i + x1i;
        br[PAD(j + 256)] = x0r - x1r;
        bi[PAD(j + 256)] = x0i - x1i;
    }
}

// --------- shared epilogue: intra-block OLA of 4 frames -> P[c][0..1792)
// y_g[p] = (p even) Yr[g][p/2] else Yi[g][p/2]; P[j] = sum_g y_g[j-256g]*win * SC
__device__ __forceinline__ void chunk_ola(float (*Yr)[NPAD], float (*Yi)[NPAD],
                                          const float* swin, float* Po, int tid) {
    const float SC = 1.0f / 512.0f;
    for (int j = tid; j < CSPAN; j += 512) {
        float acc = 0.f;
        #pragma unroll
        for (int gg = 0; gg < CHUNKF; ++gg) {
            int p = j - 256 * gg;
            if (p >= 0 && p < NFFT) {
                float yv = (p & 1) ? Yi[gg][PAD(p >> 1)] : Yr[gg][PAD(p >> 1)];
                acc += yv * swin[p];
            }
        }
        Po[j] = acc * SC;
    }
}

// -------------------- init: P0 from mag * e^{i 2pi ang} (irfft via c512, per chunk)
__global__ __launch_bounds__(512) void k_init4(
        const float* __restrict__ mag, const float* __restrict__ ang,
        const float* __restrict__ gtwr, const float* __restrict__ gtwi,
        const float* __restrict__ gt5r, const float* __restrict__ gt5i,
        const float* __restrict__ win, float* __restrict__ Pout) {
    __shared__ float swin[NFFT];
    __shared__ float Xr[CHUNKF][NPAD], Xi[CHUNKF][NPAD];
    __shared__ float Yr[CHUNKF][NPAD], Yi[CHUNKF][NPAD];
    __shared__ float t5r[128], t5i[128];
    int blk = blockIdx.x; int b = blk >> 8; int c = blk & (NCHUNK - 1);
    int tid = threadIdx.x; int g = tid >> 7; int l = tid & 127;
    if (tid < 128) { t5r[tid] = gt5r[tid]; t5i[tid] = gt5i[tid]; }
    for (int q = tid; q < NFFT; q += 512) swin[q] = win[q];
    int ft = CHUNKF * c + g;
    const float* mrow = mag + (size_t)(b * TFRAMES + ft) * NFREQ;
    const float TWO_PI = 6.283185307179586477f;
    if (l == 0) {
        float a0, s0, c0;
        a0 = ang[((size_t)(b * NFREQ + 0)) * TFRAMES + ft] * TWO_PI;
        sincosf(a0, &s0, &c0);
        float p0 = mrow[0] * c0;
        a0 = ang[((size_t)(b * NFREQ + 512)) * TFRAMES + ft] * TWO_PI;
        sincosf(a0, &s0, &c0);
        float p512 = mrow[512] * c0;
        Xr[g][PAD(0)] = 0.5f * (p0 + p512);
        Xi[g][PAD(0)] = 0.5f * (p0 - p512);
        a0 = ang[((size_t)(b * NFREQ + 256)) * TFRAMES + ft] * TWO_PI;
        sincosf(a0, &s0, &c0);
        Xr[g][PAD(256)] = mrow[256] * c0;
        Xi[g][PAD(256)] = -(mrow[256] * s0);
    }
    #pragma unroll
    for (int q2 = 0; q2 < 2; ++q2) {
        int k = l + q2 * 128;
        if (k == 0) continue;
        int j = 512 - k;
        float ak = ang[((size_t)(b * NFREQ + k)) * TFRAMES + ft] * TWO_PI;
        float aj = ang[((size_t)(b * NFREQ + j)) * TFRAMES + ft] * TWO_PI;
        float sk, ck, sj, cj;
        sincosf(ak, &sk, &ck); sincosf(aj, &sj, &cj);
        float pkr = mrow[k] * ck, pki = mrow[k] * sk;
        float pjr = mrow[j] * cj, pji = mrow[j] * sj;
        float Wr = gtwr[k], Wi = gtwi[k];
        float Cr = 0.5f * (pkr + pjr), Ci = 0.5f * (pki - pji);
        float Dr = 0.5f * (pkr - pjr), Di = 0.5f * (pki + pji);
        float U = Wr * Di - Wi * Dr, V = Wr * Dr + Wi * Di;
        Xr[g][PAD(k)] = Cr - U;  Xi[g][PAD(k)] = Ci + V;
        Xr[g][PAD(j)] = Cr + U;  Xi[g][PAD(j)] = -Ci + V;
    }
    fft512_m(Xr[g], Xi[g], Yr[g], Yi[g], t5r, t5i, l, -1.f);   // inverse
    __syncthreads();
    chunk_ola(Yr, Yi, swin, Pout + ((size_t)b * NCHUNK + c) * CSPAN, tid);
}

// -------- one GL iteration per chunk: stage window from Pin -> 4x (rfft,
// project, irfft) -> intra-block OLA -> Pout[c]. No atomics, no races.
__global__ __launch_bounds__(512) void k_gl4(
        const float* __restrict__ Pin, const float* __restrict__ mag,
        const float* __restrict__ envinv,
        const float* __restrict__ gtwr, const float* __restrict__ gtwi,
        const float* __restrict__ gt5r, const float* __restrict__ gt5i,
        const float* __restrict__ win, float* __restrict__ Pout) {
    __shared__ float sigwin[CSPAN];
    __shared__ float swin[NFFT];
    __shared__ float Xr[CHUNKF][NPAD], Xi[CHUNKF][NPAD];
    __shared__ float Yr[CHUNKF][NPAD], Yi[CHUNKF][NPAD];
    __shared__ float t5r[128], t5i[128];
    int blk = blockIdx.x; int b = blk >> 8; int c = blk & (NCHUNK - 1);
    int tid = threadIdx.x; int g = tid >> 7; int l = tid & 127;
    if (tid < 128) { t5r[tid] = gt5r[tid]; t5i[tid] = gt5i[tid]; }
    for (int q = tid; q < NFFT; q += 512) swin[q] = win[q];
    // ---- stage normalized signal window for padded coords [1024c, 1024c+1792)
    // contributors of pp = 1024c+q: chunk c (j=q); c-1 (j=q+1024, iff q<768);
    // c+1 (j=q-1024, iff q>=1024).
    const float* Pb = Pin + (size_t)b * NCHUNK * CSPAN;
    for (int q = tid; q < CSPAN; q += 512) {
        float v = Pb[c * CSPAN + q];
        if (q < 768 && c > 0)              v += Pb[(c - 1) * CSPAN + q + 1024];
        if (q >= 1024 && c < NCHUNK - 1)   v += Pb[(c + 1) * CSPAN + q - 1024];
        sigwin[q] = v * envinv[1024 * c + q];
    }
    __syncthreads();
    // ---- z-pack per group: z[m] = s[2m]w[2m] + i s[2m+1]w[2m+1]
    // (reflect-mapped coords provably stay inside this chunk's sigwin)
    #pragma unroll
    for (int r = 0; r < 4; ++r) {
        int m = l + r * 128;
        float sv[2];
        #pragma unroll
        for (int h = 0; h < 2; ++h) {
            int j = 2 * m + h;
            int pp = 1024 * c + 256 * g + j;
            int u = pp - PADW;
            if (u < 0) u = -u;
            else if (u >= LOUT) u = 2 * LOUT - 2 - u;
            int q = u + PADW - 1024 * c;
            sv[h] = sigwin[q];
        }
        Xr[g][PAD(m)] = sv[0] * swin[2 * m];
        Xi[g][PAD(m)] = sv[1] * swin[2 * m + 1];
    }
    int ft = CHUNKF * c + g;
    fft512_m(Xr[g], Xi[g], Yr[g], Yi[g], t5r, t5i, l, +1.f);   // forward; Z in Y
    __syncthreads();
    // ---- unpack rfft bins, project to mag, repack inverse input into X
    // (no barriers here: reads Y / writes X, disjoint indices per thread;
    //  fft's leading barrier orders everything — round-3 lesson)
    const float* mrow = mag + (size_t)(b * TFRAMES + ft) * NFREQ;
    if (l == 0) {
        float Z0r = Yr[g][PAD(0)], Z0i = Yi[g][PAD(0)];
        float X0 = Z0r + Z0i, X512 = Z0r - Z0i;
        float p0   = mrow[0]   * X0   / (fabsf(X0)   + 1e-8f);
        float p512 = mrow[512] * X512 / (fabsf(X512) + 1e-8f);
        float Zcr = Yr[g][PAD(256)], Zci = Yi[g][PAD(256)];
        float X256r = Zcr, X256i = -Zci;
        float sc = mrow[256] / (sqrtf(X256r * X256r + X256i * X256i) + 1e-8f);
        Xr[g][PAD(0)] = 0.5f * (p0 + p512);
        Xi[g][PAD(0)] = 0.5f * (p0 - p512);
        Xr[g][PAD(256)] = X256r * sc;
        Xi[g][PAD(256)] = -(X256i * sc);
    }
    #pragma unroll
    for (int q2 = 0; q2 < 2; ++q2) {
        int k = l + q2 * 128;
        if (k == 0) continue;
        int j = 512 - k;
        float Zar = Yr[g][PAD(k)], Zai = Yi[g][PAD(k)];
        float Zbr = Yr[g][PAD(j)], Zbi = Yi[g][PAD(j)];
        float Ar = 0.5f * (Zar + Zbr), Ai = 0.5f * (Zai - Zbi);
        float Br = 0.5f * (Zar - Zbr), Bi = 0.5f * (Zai + Zbi);
        float Wr = gtwr[k], Wi = gtwi[k];
        float P = Wr * Bi + Wi * Br, Q = Wr * Br - Wi * Bi;
        float Xkr = Ar + P, Xki = Ai - Q;
        float Xjr = Ar - P, Xji = -Ai - Q;
        float sck = mrow[k] / (sqrtf(Xkr * Xkr + Xki * Xki) + 1e-8f);
        float scj = mrow[j] / (sqrtf(Xjr * Xjr + Xji * Xji) + 1e-8f);
        float pkr = Xkr * sck, pki = Xki * sck;
        float pjr = Xjr * scj, pji = Xji * scj;
        float Cr = 0.5f * (pkr + pjr), Ci = 0.5f * (pki - pji);
        float Dr = 0.5f * (pkr - pjr), Di = 0.5f * (pki + pji);
        float U = Wr * Di - Wi * Dr, V = Wr * Dr + Wi * Di;
        Xr[g][PAD(k)] = Cr - U;  Xi[g][PAD(k)] = Ci + V;
        Xr[g][PAD(j)] = Cr + U;  Xi[g][PAD(j)] = -Ci + V;
    }
    fft512_m(Xr[g], Xi[g], Yr[g], Yi[g], t5r, t5i, l, -1.f);   // inverse
    __syncthreads();                                           // Y read cross-group below
    chunk_ola(Yr, Yi, swin, Pout + ((size_t)b * NCHUNK + c) * CSPAN, tid);
}

// -------------------- final output: out[i] = (<=2 P contributions) * envinv
__global__ void k_out(const float* __restrict__ P, const float* __restrict__ envinv,
                      float* __restrict__ out) {
    int i = blockIdx.x * 256 + threadIdx.x;
    int b = blockIdx.y;
    if (i >= LOUT) return;
    int ii = i + PADW;
    int c = ii >> 10; if (c > NCHUNK - 1) c = NCHUNK - 1;
    const float* Pb = P + (size_t)b * NCHUNK * CSPAN;
    int j = ii - 1024 * c;                       // < 1792 guaranteed
    float v = Pb[c * CSPAN + j];
    if (c > 0) {
        int j2 = j + 1024;
        if (j2 < CSPAN) v += Pb[(c - 1) * CSPAN + j2];
    }
    out[(size_t)b * LOUT + i] = v * envinv[ii];
}

// ---------------------------------------------------------------------- host
extern "C" void kernel_launch(void* const* d_in, const int* in_sizes, int n_in,
                              void* d_out, int out_size, void* d_ws, size_t ws_size,
                              hipStream_t stream) {
    const float* mel = (const float*)d_in[0];   // (8, 80, 1024)
    const float* ang = (const float*)d_in[1];   // (8, 513, 1024)
    const float* fb  = (const float*)d_in[2];   // (513, 80)
    float* ws = (float*)d_ws;

    float* twr    = ws;                                   // 512   (W_1024)
    float* twi    = twr + NHALF;                          // 512
    float* t5r    = twi + NHALF;                          // 128   (W_512)
    float* t5i    = t5r + 128;                            // 128
    float* win    = t5i + 128;                            // 1024
    float* fbT    = win + NFFT;                           // 80*513
    float* envinv = fbT + NMELS * NFREQ;                  // LPAD
    float* mag    = envinv + LPAD;                        // 8*1024*513
    float* PA     = mag + (size_t)BATCH * TFRAMES * NFREQ;    // 8*256*1792
    float* PB     = PA + (size_t)BATCH * NCHUNK * CSPAN;      // 8*256*1792
    float* out    = (float*)d_out;

    k_init_tables<<<4, 256, 0, stream>>>(twr, twi, t5r, t5i, win);
    k_env<<<(LPAD + 255) / 256, 256, 0, stream>>>(win, envinv);
    k_fbt<<<(NFREQ * NMELS + 255) / 256, 256, 0, stream>>>(fb, fbT);
    {
        dim3 g(TFRAMES / 16, BATCH);
        k_mag<<<g, 256, 0, stream>>>(mel, fbT, mag);
    }
    k_init4<<<BATCH * NCHUNK, 512, 0, stream>>>(mag, ang, twr, twi, t5r, t5i, win, PA);

    float* fin = PA;
    float* fout = PB;
    for (int it = 0; it < NITER; ++it) {
        k_gl4<<<BATCH * NCHUNK, 512, 0, stream>>>(fin, mag, envinv, twr, twi,
                                                  t5r, t5i, win, fout);
        float* tmp = fin; fin = fout; fout = tmp;
    }
    // NITER even -> final P in PA (== fin)
    dim3 og((LOUT + 255) / 256, BATCH);
    k_out<<<og, 256, 0, stream>>>(fin, envinv, out);
}

// Round 7
// 2211.902 us; speedup vs baseline: 1.7910x; 1.1876x over previous
//
#include <hip/hip_runtime.h>
#include <math.h>

#define NFFT   1024
#define NHALF  512
#define HOPSZ  256
#define NMELS  80
#define NFREQ  513
#define BATCH  8
#define TFRAMES 1024
#define PADW   512
#define LPAD   (NFFT + (TFRAMES - 1) * HOPSZ)   // 262912
#define LOUT   (LPAD - 2 * PADW)                // 261888
#define NITER  60
#define PI_D   3.14159265358979323846

#define CHUNKF 4                                // frames per chunk
#define CSPAN  1792                             // 1024 + 3*256
#define NCHUNK (TFRAMES / CHUNKF)               // 256

// padding for the (old, init-only) radix-4 FFT
#define PAD(p) ((p) + ((p) >> 5))
#define NPAD   (NHALF + (NHALF >> 5))           // 528

// ---------------------------------------------------------------- init tables
__global__ void k_init_tables(float* __restrict__ twr, float* __restrict__ twi,
                              float* __restrict__ t5r, float* __restrict__ t5i,
                              float* __restrict__ win) {
    int j = blockIdx.x * 256 + threadIdx.x;
    if (j < NHALF) {
        double th = -2.0 * PI_D * (double)j / (double)NFFT;
        twr[j] = (float)cos(th);
        twi[j] = (float)sin(th);
    }
    if (j < 128) {
        double th = -2.0 * PI_D * (double)j / 512.0;
        t5r[j] = (float)cos(th);
        t5i[j] = (float)sin(th);
    }
    if (j < NFFT) {
        win[j] = (float)(0.5 - 0.5 * cos(2.0 * PI_D * (double)j / (double)NFFT));
    }
}

__global__ void k_env(const float* __restrict__ win, float* __restrict__ envinv) {
    int i = blockIdx.x * 256 + threadIdx.x;
    if (i >= LPAD) return;
    int thi = i / HOPSZ; if (thi > TFRAMES - 1) thi = TFRAMES - 1;
    int d = i - (NFFT - 1);
    int tlo = (d > 0) ? (d + HOPSZ - 1) / HOPSZ : 0;
    float e = 0.f;
    for (int t = tlo; t <= thi; ++t) { float w = win[i - t * HOPSZ]; e += w * w; }
    envinv[i] = (e > 1e-11f) ? (1.0f / e) : 1.0f;
}

__global__ void k_fbt(const float* __restrict__ fb, float* __restrict__ fbT) {
    int i = blockIdx.x * 256 + threadIdx.x;
    if (i < NFREQ * NMELS) {
        int k = i / NMELS, m = i - k * NMELS;
        fbT[m * NFREQ + k] = fb[i];
    }
}

// mag[(b*1024+t)*513+k], tiled 16 t per block
__global__ __launch_bounds__(256) void k_mag(const float* __restrict__ mel,
                                             const float* __restrict__ fbT,
                                             float* __restrict__ mag) {
    __shared__ float sm[NMELS * 16];
    int b = blockIdx.y, t0 = blockIdx.x * 16, tid = threadIdx.x;
    for (int idx = tid; idx < NMELS * 16; idx += 256) {
        int m = idx >> 4, tt = idx & 15;
        sm[idx] = expf(mel[(size_t)(b * NMELS + m) * TFRAMES + (t0 + tt)]);
    }
    __syncthreads();
    for (int k = tid; k < NFREQ; k += 256) {
        float acc[16];
        #pragma unroll
        for (int tt = 0; tt < 16; ++tt) acc[tt] = 0.f;
        for (int m = 0; m < NMELS; ++m) {
            float w = fbT[m * NFREQ + k];
            #pragma unroll
            for (int tt = 0; tt < 16; ++tt) acc[tt] += w * sm[m * 16 + tt];
        }
        #pragma unroll
        for (int tt = 0; tt < 16; ++tt)
            mag[(size_t)((b << 10) + t0 + tt) * NFREQ + k] = fmaxf(acc[tt], 0.f);
    }
}

// ===================== old radix-4 path (init kernel only, verified round 6)
__device__ __forceinline__ void fft512_m(float* xr, float* xi, float* yr, float* yi,
                                         const float* t5r, const float* t5i,
                                         int l, float sgn) {
    float *ar = xr, *ai = xi, *br = yr, *bi = yi;
    #pragma unroll
    for (int st = 0; st < 4; ++st) {
        int s = 1 << (2 * st);
        __syncthreads();
        int j = l;
        int hi = j & ~(s - 1);
        int o1 = j + 3 * hi;
        float v0r = ar[PAD(j)],       v0i = ai[PAD(j)];
        float v1r = ar[PAD(j + 128)], v1i = ai[PAD(j + 128)];
        float v2r = ar[PAD(j + 256)], v2i = ai[PAD(j + 256)];
        float v3r = ar[PAD(j + 384)], v3i = ai[PAD(j + 384)];
        float a_r = v0r + v2r, a_i = v0i + v2i;
        float b_r = v0r - v2r, b_i = v0i - v2i;
        float c_r = v1r + v3r, c_i = v1i + v3i;
        float d_r = v1r - v3r, d_i = v1i - v3i;
        float X0r = a_r + c_r, X0i = a_i + c_i;
        float X2r = a_r - c_r, X2i = a_i - c_i;
        float X1r = b_r + sgn * d_i, X1i = b_i - sgn * d_r;
        float X3r = b_r - sgn * d_i, X3i = b_i + sgn * d_r;
        float w1r = t5r[hi], w1i = sgn * t5i[hi];
        float w2r = w1r * w1r - w1i * w1i, w2i = 2.f * w1r * w1i;
        float w3r = w2r * w1r - w2i * w1i, w3i = w2r * w1i + w2i * w1r;
        br[PAD(o1)]         = X0r;
        bi[PAD(o1)]         = X0i;
        br[PAD(o1 + s)]     = X1r * w1r - X1i * w1i;
        bi[PAD(o1 + s)]     = X1r * w1i + X1i * w1r;
        br[PAD(o1 + 2*s)]   = X2r * w2r - X2i * w2i;
        bi[PAD(o1 + 2*s)]   = X2r * w2i + X2i * w2r;
        br[PAD(o1 + 3*s)]   = X3r * w3r - X3i * w3i;
        bi[PAD(o1 + 3*s)]   = X3r * w3i + X3i * w3r;
        float* t0 = ar; ar = br; br = t0;
        float* t1 = ai; ai = bi; bi = t1;
    }
    __syncthreads();
    #pragma unroll
    for (int r = 0; r < 2; ++r) {
        int j = l + r * 128;
        float x0r = ar[PAD(j)],       x0i = ai[PAD(j)];
        float x1r = ar[PAD(j + 256)], x1i = ai[PAD(j + 256)];
        br[PAD(j)]       = x0r + x1r;
        bi[PAD(j)]       = x0i + x1i;
        br[PAD(j + 256)] = x0r - x1r;
        bi[PAD(j + 256)] = x0i - x1i;
    }
}

__device__ __forceinline__ void chunk_ola4(float (*Yr)[NPAD], float (*Yi)[NPAD],
                                           const float* swin, float* Po, int tid) {
    const float SC = 1.0f / 512.0f;
    for (int j = tid; j < CSPAN; j += 512) {
        float acc = 0.f;
        #pragma unroll
        for (int gg = 0; gg < CHUNKF; ++gg) {
            int p = j - 256 * gg;
            if (p >= 0 && p < NFFT) {
                float yv = (p & 1) ? Yi[gg][PAD(p >> 1)] : Yr[gg][PAD(p >> 1)];
                acc += yv * swin[p];
            }
        }
        Po[j] = acc * SC;
    }
}

// -------------------- init: P0 from mag * e^{i 2pi ang} (verified round 6)
__global__ __launch_bounds__(512) void k_init4(
        const float* __restrict__ mag, const float* __restrict__ ang,
        const float* __restrict__ gtwr, const float* __restrict__ gtwi,
        const float* __restrict__ gt5r, const float* __restrict__ gt5i,
        const float* __restrict__ win, float* __restrict__ Pout) {
    __shared__ float swin[NFFT];
    __shared__ float Xr[CHUNKF][NPAD], Xi[CHUNKF][NPAD];
    __shared__ float Yr[CHUNKF][NPAD], Yi[CHUNKF][NPAD];
    __shared__ float t5r[128], t5i[128];
    int blk = blockIdx.x; int b = blk >> 8; int c = blk & (NCHUNK - 1);
    int tid = threadIdx.x; int g = tid >> 7; int l = tid & 127;
    if (tid < 128) { t5r[tid] = gt5r[tid]; t5i[tid] = gt5i[tid]; }
    for (int q = tid; q < NFFT; q += 512) swin[q] = win[q];
    int ft = CHUNKF * c + g;
    const float* mrow = mag + (size_t)(b * TFRAMES + ft) * NFREQ;
    const float TWO_PI = 6.283185307179586477f;
    if (l == 0) {
        float a0, s0, c0;
        a0 = ang[((size_t)(b * NFREQ + 0)) * TFRAMES + ft] * TWO_PI;
        sincosf(a0, &s0, &c0);
        float p0 = mrow[0] * c0;
        a0 = ang[((size_t)(b * NFREQ + 512)) * TFRAMES + ft] * TWO_PI;
        sincosf(a0, &s0, &c0);
        float p512 = mrow[512] * c0;
        Xr[g][PAD(0)] = 0.5f * (p0 + p512);
        Xi[g][PAD(0)] = 0.5f * (p0 - p512);
        a0 = ang[((size_t)(b * NFREQ + 256)) * TFRAMES + ft] * TWO_PI;
        sincosf(a0, &s0, &c0);
        Xr[g][PAD(256)] = mrow[256] * c0;
        Xi[g][PAD(256)] = -(mrow[256] * s0);
    }
    #pragma unroll
    for (int q2 = 0; q2 < 2; ++q2) {
        int k = l + q2 * 128;
        if (k == 0) continue;
        int j = 512 - k;
        float ak = ang[((size_t)(b * NFREQ + k)) * TFRAMES + ft] * TWO_PI;
        float aj = ang[((size_t)(b * NFREQ + j)) * TFRAMES + ft] * TWO_PI;
        float sk, ck, sj, cj;
        sincosf(ak, &sk, &ck); sincosf(aj, &sj, &cj);
        float pkr = mrow[k] * ck, pki = mrow[k] * sk;
        float pjr = mrow[j] * cj, pji = mrow[j] * sj;
        float Wr = gtwr[k], Wi = gtwi[k];
        float Cr = 0.5f * (pkr + pjr), Ci = 0.5f * (pki - pji);
        float Dr = 0.5f * (pkr - pjr), Di = 0.5f * (pki + pji);
        float U = Wr * Di - Wi * Dr, V = Wr * Dr + Wi * Di;
        Xr[g][PAD(k)] = Cr - U;  Xi[g][PAD(k)] = Ci + V;
        Xr[g][PAD(j)] = Cr + U;  Xi[g][PAD(j)] = -Ci + V;
    }
    fft512_m(Xr[g], Xi[g], Yr[g], Yi[g], t5r, t5i, l, -1.f);
    __syncthreads();
    chunk_ola4(Yr, Yi, swin, Pout + ((size_t)b * NCHUNK + c) * CSPAN, tid);
}

// ===================== new wave-local radix-8 machinery (hot loop) ==========
__device__ __forceinline__ float2 cmul(float2 a, float2 b) {
    return make_float2(a.x * b.x - a.y * b.y, a.x * b.y + a.y * b.x);
}

// in-register 8-pt DFT; sgn=+1 forward, -1 inverse. (spot-checked vs W_8^k)
__device__ __forceinline__ void dft8(float2 v[8], float sgn) {
    const float s2 = 0.70710678118654752f;
    // even dft4 on v0,v2,v4,v6
    float ar = v[0].x + v[4].x, ai = v[0].y + v[4].y;
    float br = v[0].x - v[4].x, bi = v[0].y - v[4].y;
    float cr = v[2].x + v[6].x, ci = v[2].y + v[6].y;
    float dr = v[2].x - v[6].x, di = v[2].y - v[6].y;
    float2 E0 = make_float2(ar + cr, ai + ci);
    float2 E2 = make_float2(ar - cr, ai - ci);
    float2 E1 = make_float2(br + sgn * di, bi - sgn * dr);
    float2 E3 = make_float2(br - sgn * di, bi + sgn * dr);
    // odd dft4 on v1,v3,v5,v7
    float ar2 = v[1].x + v[5].x, ai2 = v[1].y + v[5].y;
    float br2 = v[1].x - v[5].x, bi2 = v[1].y - v[5].y;
    float cr2 = v[3].x + v[7].x, ci2 = v[3].y + v[7].y;
    float dr2 = v[3].x - v[7].x, di2 = v[3].y - v[7].y;
    float2 O0 = make_float2(ar2 + cr2, ai2 + ci2);
    float2 O2 = make_float2(ar2 - cr2, ai2 - ci2);
    float2 O1 = make_float2(br2 + sgn * di2, bi2 - sgn * dr2);
    float2 O3 = make_float2(br2 - sgn * di2, bi2 + sgn * dr2);
    // W8^k * Ok
    float2 T1 = make_float2((O1.x + sgn * O1.y) * s2, (O1.y - sgn * O1.x) * s2);
    float2 T2 = make_float2(sgn * O2.y, -sgn * O2.x);
    float2 T3 = make_float2((-O3.x + sgn * O3.y) * s2, (-O3.y - sgn * O3.x) * s2);
    v[0] = make_float2(E0.x + O0.x, E0.y + O0.y);
    v[4] = make_float2(E0.x - O0.x, E0.y - O0.y);
    v[1] = make_float2(E1.x + T1.x, E1.y + T1.y);
    v[5] = make_float2(E1.x - T1.x, E1.y - T1.y);
    v[2] = make_float2(E2.x + T2.x, E2.y + T2.y);
    v[6] = make_float2(E2.x - T2.x, E2.y - T2.y);
    v[3] = make_float2(E3.x + T3.x, E3.y + T3.y);
    v[7] = make_float2(E3.x - T3.x, E3.y - T3.y);
}

// apply v[m] *= W^m for m=1..7, W=(wr,wi)
__device__ __forceinline__ void twchain(float2 v[8], float wr, float wi) {
    float2 w = make_float2(wr, wi), cur = w;
    #pragma unroll
    for (int m = 1; m < 8; ++m) { v[m] = cmul(v[m], cur); cur = cmul(cur, w); }
}

// Stockham radix-8 stages 2&3 (s=8 in-place scatter, s=64 in-place).
// C is this wave's private 512-complex LDS buffer; wave-local ordering
// (single instruction stream) makes read-all-then-write-all in-place safe.
__device__ __forceinline__ void fft512_r8_tail(float2* Cb, const float* gtwr,
                                               const float* gtwi, int t, float sgn) {
    float2 u[8];
    // stage s=8
    #pragma unroll
    for (int m = 0; m < 8; ++m) u[m] = Cb[t + 64 * m];
    dft8(u, sgn);
    int a = t >> 3;
    twchain(u, gtwr[16 * a], sgn * gtwi[16 * a]);      // W_64^a = W_1024^{16a}
    int o1 = 64 * a + (t & 7);
    #pragma unroll
    for (int m = 0; m < 8; ++m) Cb[o1 + 8 * m] = u[m];
    // stage s=64 (twiddle-free, in-place same indices)
    #pragma unroll
    for (int m = 0; m < 8; ++m) u[m] = Cb[t + 64 * m];
    dft8(u, sgn);
    #pragma unroll
    for (int m = 0; m < 8; ++m) Cb[t + 64 * m] = u[m];
}

// -------- hot GL iteration: one wave per frame, radix-8 wave-local FFTs
__global__ __launch_bounds__(256, 4) void k_gl8(
        const float* __restrict__ Pin, const float* __restrict__ mag,
        const float* __restrict__ envinv,
        const float* __restrict__ gtwr, const float* __restrict__ gtwi,
        const float* __restrict__ win, float* __restrict__ Pout) {
    __shared__ float sigwin[CSPAN];
    __shared__ float swin[NFFT];
    __shared__ float2 C[CHUNKF][512];
    int blk = blockIdx.x; int b = blk >> 8; int c = blk & (NCHUNK - 1);
    int tid = threadIdx.x; int g = tid >> 6; int t = tid & 63;
    // ---- stage normalized signal window (identical to verified round 6)
    const float* Pb = Pin + (size_t)b * NCHUNK * CSPAN;
    for (int q = tid; q < CSPAN; q += 256) {
        float v = Pb[c * CSPAN + q];
        if (q < 768 && c > 0)              v += Pb[(c - 1) * CSPAN + q + 1024];
        if (q >= 1024 && c < NCHUNK - 1)   v += Pb[(c + 1) * CSPAN + q - 1024];
        sigwin[q] = v * envinv[1024 * c + q];
    }
    for (int q = tid; q < NFFT; q += 256) swin[q] = win[q];
    __syncthreads();
    float2* Cb = C[g];
    int ft = CHUNKF * c + g;
    const float* mrow = mag + (size_t)(b * TFRAMES + ft) * NFREQ;
    // ---- forward stage s=1 fused with z-pack (inputs straight to registers)
    float2 v[8];
    #pragma unroll
    for (int m = 0; m < 8; ++m) {
        int mp = t + 64 * m;
        int js = 2 * mp;
        float sv[2];
        #pragma unroll
        for (int h = 0; h < 2; ++h) {
            int pp = 1024 * c + 256 * g + js + h;
            int u = pp - PADW;
            if (u < 0) u = -u;
            else if (u >= LOUT) u = 2 * LOUT - 2 - u;
            sv[h] = sigwin[u + PADW - 1024 * c];
        }
        v[m] = make_float2(sv[0] * swin[js], sv[1] * swin[js + 1]);
    }
    dft8(v, +1.f);
    twchain(v, gtwr[2 * t], gtwi[2 * t]);               // W_512^t = W_1024^{2t}
    #pragma unroll
    for (int m = 0; m < 8; ++m) Cb[8 * t + m] = v[m];
    fft512_r8_tail(Cb, gtwr, gtwi, t, +1.f);            // Z in Cb, natural order
    // ---- projection fused into inverse stage s=1 (per-bin general formula,
    //      algebra proven identical to round-6 k/j branches)
    float2 Zp[8], Zq[8];
    #pragma unroll
    for (int m = 0; m < 8; ++m) {
        int p = t + 64 * m;
        Zp[m] = Cb[p];
        Zq[m] = Cb[(512 - p) & 511];
    }
    #pragma unroll
    for (int m = 0; m < 8; ++m) {
        int p = t + 64 * m, q = 512 - p;
        float Ar = 0.5f * (Zp[m].x + Zq[m].x), Ai = 0.5f * (Zp[m].y - Zq[m].y);
        float Br = 0.5f * (Zp[m].x - Zq[m].x), Bi = 0.5f * (Zp[m].y + Zq[m].y);
        float Wr = gtwr[p & 511], Wi = gtwi[p & 511];
        float P = Wr * Bi + Wi * Br, Q = Wr * Br - Wi * Bi;
        float Xpr = Ar + P, Xpi = Ai - Q;
        float Xqr = Ar - P, Xqi = -Ai - Q;
        float scp = mrow[p] / (sqrtf(Xpr * Xpr + Xpi * Xpi) + 1e-8f);
        float scq = mrow[q & 1023] / (sqrtf(Xqr * Xqr + Xqi * Xqi) + 1e-8f);
        float ppr = Xpr * scp, ppi = Xpi * scp;
        float pqr = Xqr * scq, pqi = Xqi * scq;
        float Cr = 0.5f * (ppr + pqr), Ci = 0.5f * (ppi - pqi);
        float Dr = 0.5f * (ppr - pqr), Di = 0.5f * (ppi + pqi);
        float U = Wr * Di - Wi * Dr, V = Wr * Dr + Wi * Di;
        v[m] = make_float2(Cr - U, Ci + V);
    }
    if (t == 0) {
        // p=0: DC+Nyquist pack (imag dropped per irfft semantics)
        float2 Z0 = Zp[0];
        float X0 = Z0.x + Z0.y, X512 = Z0.x - Z0.y;
        float p0   = mrow[0]   * X0   / (fabsf(X0)   + 1e-8f);
        float p512 = mrow[512] * X512 / (fabsf(X512) + 1e-8f);
        v[0] = make_float2(0.5f * (p0 + p512), 0.5f * (p0 - p512));
        // p=256: X256 = conj(Z256); Zinv[256] = conj(proj)
        float2 Zc = Zp[4];
        float X256r = Zc.x, X256i = -Zc.y;
        float sc = mrow[256] / (sqrtf(X256r * X256r + X256i * X256i) + 1e-8f);
        v[4] = make_float2(X256r * sc, -(X256i * sc));
    }
    dft8(v, -1.f);
    twchain(v, gtwr[2 * t], -gtwi[2 * t]);              // conj for inverse
    #pragma unroll
    for (int m = 0; m < 8; ++m) Cb[8 * t + m] = v[m];
    fft512_r8_tail(Cb, gtwr, gtwi, t, -1.f);            // z_inv in Cb
    __syncthreads();
    // ---- intra-block OLA of 4 frames -> Pout[c]  (x[2m]=re, x[2m+1]=im)
    const float SC = 1.0f / 512.0f;
    float* Po = Pout + ((size_t)b * NCHUNK + c) * CSPAN;
    for (int j = tid; j < CSPAN; j += 256) {
        float acc = 0.f;
        #pragma unroll
        for (int gg = 0; gg < CHUNKF; ++gg) {
            int p = j - 256 * gg;
            if (p >= 0 && p < NFFT) {
                float2 zz = C[gg][p >> 1];
                float yv = (p & 1) ? zz.y : zz.x;
                acc += yv * swin[p];
            }
        }
        Po[j] = acc * SC;
    }
}

// -------------------- final output (verified round 6)
__global__ void k_out(const float* __restrict__ P, const float* __restrict__ envinv,
                      float* __restrict__ out) {
    int i = blockIdx.x * 256 + threadIdx.x;
    int b = blockIdx.y;
    if (i >= LOUT) return;
    int ii = i + PADW;
    int c = ii >> 10; if (c > NCHUNK - 1) c = NCHUNK - 1;
    const float* Pb = P + (size_t)b * NCHUNK * CSPAN;
    int j = ii - 1024 * c;
    float v = Pb[c * CSPAN + j];
    if (c > 0) {
        int j2 = j + 1024;
        if (j2 < CSPAN) v += Pb[(c - 1) * CSPAN + j2];
    }
    out[(size_t)b * LOUT + i] = v * envinv[ii];
}

// ---------------------------------------------------------------------- host
extern "C" void kernel_launch(void* const* d_in, const int* in_sizes, int n_in,
                              void* d_out, int out_size, void* d_ws, size_t ws_size,
                              hipStream_t stream) {
    const float* mel = (const float*)d_in[0];   // (8, 80, 1024)
    const float* ang = (const float*)d_in[1];   // (8, 513, 1024)
    const float* fb  = (const float*)d_in[2];   // (513, 80)
    float* ws = (float*)d_ws;

    float* twr    = ws;                                   // 512   (W_1024)
    float* twi    = twr + NHALF;                          // 512
    float* t5r    = twi + NHALF;                          // 128   (W_512, init)
    float* t5i    = t5r + 128;                            // 128
    float* win    = t5i + 128;                            // 1024
    float* fbT    = win + NFFT;                           // 80*513
    float* envinv = fbT + NMELS * NFREQ;                  // LPAD
    float* mag    = envinv + LPAD;                        // 8*1024*513
    float* PA     = mag + (size_t)BATCH * TFRAMES * NFREQ;    // 8*256*1792
    float* PB     = PA + (size_t)BATCH * NCHUNK * CSPAN;      // 8*256*1792
    float* out    = (float*)d_out;

    k_init_tables<<<4, 256, 0, stream>>>(twr, twi, t5r, t5i, win);
    k_env<<<(LPAD + 255) / 256, 256, 0, stream>>>(win, envinv);
    k_fbt<<<(NFREQ * NMELS + 255) / 256, 256, 0, stream>>>(fb, fbT);
    {
        dim3 g(TFRAMES / 16, BATCH);
        k_mag<<<g, 256, 0, stream>>>(mel, fbT, mag);
    }
    k_init4<<<BATCH * NCHUNK, 512, 0, stream>>>(mag, ang, twr, twi, t5r, t5i, win, PA);

    float* fin = PA;
    float* fout = PB;
    for (int it = 0; it < NITER; ++it) {
        k_gl8<<<BATCH * NCHUNK, 256, 0, stream>>>(fin, mag, envinv, twr, twi,
                                                  win, fout);
        float* tmp = fin; fin = fout; fout = tmp;
    }
    dim3 og((LOUT + 255) / 256, BATCH);
    k_out<<<og, 256, 0, stream>>>(fin, envinv, out);
}